// Round 4
// baseline (100.111 us; speedup 1.0000x reference)
//
#include <hip/hip_runtime.h>
#include <hip/hip_bf16.h>

// Problem constants (from reference)
#define N_BITS   1024
#define CHANNELS 16
#define WIDTH    512
#define HEIGHT   512
#define MAPSZ    (WIDTH * HEIGHT)   // 262144 floats = 1 MiB per (n,c) plane
#define BATCH    32

typedef float f32x4 __attribute__((ext_vector_type(4)));

// One block per (n,c) plane: 512 blocks total (2/CU resident), each block
// streams a single contiguous 1 MiB region. Pattern (1024 floats) lives in
// registers: one f32x4 per thread of a 256-thread block. Few, long, linear
// write streams — matching the fill kernel's 6.6+ TB/s regime (R3 showed
// 4096 short streams stall at 5.44 TB/s regardless of NT vs writeback).

__global__ __launch_bounds__(256) void lte_fill_kernel(
    const float* __restrict__ bits, float* __restrict__ out)
{
    const int tid = threadIdx.x;             // 0..255
    const int blk = blockIdx.x;              // 0..511
    const int c   = blk & (CHANNELS - 1);
    const int n   = blk / CHANNELS;
    (void)c;

    // Pattern chunk: bits[n, tid*4 .. tid*4+3] -> 4 floats in {0,1}
    const f32x4 bv = reinterpret_cast<const f32x4*>(bits + (size_t)n * N_BITS)[tid];
    f32x4 p;
    p.x = (fabsf(bv.x) > 0.5f) ? 1.0f : 0.0f;
    p.y = (fabsf(bv.y) > 0.5f) ? 1.0f : 0.0f;
    p.z = (fabsf(bv.z) > 0.5f) ? 1.0f : 0.0f;
    p.w = (fabsf(bv.w) > 0.5f) ? 1.0f : 0.0f;

    // This block's plane: out + blk * MAPSZ floats (planes are contiguous,
    // blk == n*CHANNELS + c exactly matches plane order).
    const size_t plane_f4 = MAPSZ / 4;       // 65536 f32x4
    f32x4* __restrict__ dst = reinterpret_cast<f32x4*>(out)
                            + (size_t)blk * plane_f4 + tid;

    const int reps   = (int)(plane_f4 / 256);  // 256 reps
    const int stride = N_BITS / 4;             // 256 f32x4 = 4 KB per rep

    #pragma unroll 8
    for (int r = 0; r < reps; ++r) {
        dst[(size_t)r * stride] = p;
    }
}

extern "C" void kernel_launch(void* const* d_in, const int* in_sizes, int n_in,
                              void* d_out, int out_size, void* d_ws, size_t ws_size,
                              hipStream_t stream) {
    const float* bits = (const float*)d_in[0];
    float* out = (float*)d_out;

    const int grid = BATCH * CHANNELS;  // 512 blocks, one per (n,c) plane
    lte_fill_kernel<<<grid, 256, 0, stream>>>(bits, out);
}